// Round 8
// baseline (993.021 us; speedup 1.0000x reference)
//
#include <hip/hip_runtime.h>
#include <stdint.h>
#include <stddef.h>

// VectorQuantization — N=32768, K=8192, D=256 fp32 -> int32 argmin.
// Round 12: ALL-REGISTER main kernel. Eight schedule variants (r4-r11)
// bracket 399-465 µs with MFMA busy invariant at ~199 µs (the floor) and
// LDS port time (reads 164 + DMA writes 55 = 219 µs/CU) ≈ MFMA time; wall ≈
// their SUM -> the barrier-phased LDS->MFMA dependency serializes the two
// pipes. Fix: remove LDS from the operand path entirely. The MFMA fragment
// layout is per-lane affine in global memory (lane (fr,g): row*512 +
// chunk*64 + g*16), so A and B fragments are loaded straight from global
// (L2-resident: SPLITK=4 maps each XCD to one 2MB code chunk) into the
// exact MFMA registers. No __syncthreads in the K loop; waves free-run and
// anti-phase load latency vs MFMA. LDS = 2KB epilogue reduction only.
// Accumulation order identical to r4/r11 -> bit-identical results.
// Fallback to the (passing) round-3 kernel if ws_size < 43MB.

#define N_PTS 32768
#define K_CB  8192
#define D_DIM 256
#define TM 128
#define TN 128
#define SPLITK 4
#define KCHUNK (K_CB / SPLITK)   // 2048
#define NTILES (KCHUNK / TN)     // 16

// fast-path ws layout (byte offsets; all 16B-aligned)
#define WS_XH   0
#define WS_XL   (WS_XH + N_PTS * D_DIM * 2)
#define WS_CH   (WS_XL + N_PTS * D_DIM * 2)
#define WS_CL   (WS_CH + K_CB * D_DIM * 2)
#define WS_C2   (WS_CL + K_CB * D_DIM * 2)
#define WS_PD   (WS_C2 + K_CB * 4)
#define WS_PI   (WS_PD + SPLITK * N_PTS * 4)
#define WS_END  (WS_PI + SPLITK * N_PTS * 4)   // 43,024,384 B

typedef _Float16 half4v __attribute__((ext_vector_type(4)));
typedef _Float16 half8v __attribute__((ext_vector_type(8)));
typedef float    f32x4  __attribute__((ext_vector_type(4)));

// ---------------- preprocessing (fused: split x, split codes + norms) ------

#define XBLOCKS (N_PTS * D_DIM / 4 / 256)   // 8192
#define CBLOCKS (K_CB * D_DIM / 4 / 256)    // 2048

__global__ void __launch_bounds__(256)
prep_kernel(const float* __restrict__ x, const float* __restrict__ vecs,
            _Float16* __restrict__ xh, _Float16* __restrict__ xl,
            _Float16* __restrict__ ch, _Float16* __restrict__ cl,
            float* __restrict__ c2) {
    const int b = blockIdx.x;
    if (b < XBLOCKS) {
        const int i = b * 256 + threadIdx.x;           // one float4 per thread
        const float4 v = ((const float4*)x)[i];
        half4v h = {(_Float16)v.x, (_Float16)v.y, (_Float16)v.z, (_Float16)v.w};
        half4v l = {(_Float16)((v.x - (float)h[0]) * 2048.0f),
                    (_Float16)((v.y - (float)h[1]) * 2048.0f),
                    (_Float16)((v.z - (float)h[2]) * 2048.0f),
                    (_Float16)((v.w - (float)h[3]) * 2048.0f)};
        *(half4v*)(xh + (size_t)i * 4) = h;
        *(half4v*)(xl + (size_t)i * 4) = l;
    } else {
        const int i = (b - XBLOCKS) * 256 + threadIdx.x;
        const float4 v = ((const float4*)vecs)[i];
        half4v h = {(_Float16)v.x, (_Float16)v.y, (_Float16)v.z, (_Float16)v.w};
        half4v l = {(_Float16)((v.x - (float)h[0]) * 2048.0f),
                    (_Float16)((v.y - (float)h[1]) * 2048.0f),
                    (_Float16)((v.z - (float)h[2]) * 2048.0f),
                    (_Float16)((v.w - (float)h[3]) * 2048.0f)};
        *(half4v*)(ch + (size_t)i * 4) = h;
        *(half4v*)(cl + (size_t)i * 4) = l;
        // one wave == one code row (64 lanes x float4 = 256 floats) -> norm.
        float s = v.x * v.x + v.y * v.y + v.z * v.z + v.w * v.w;
#pragma unroll
        for (int off = 32; off > 0; off >>= 1) s += __shfl_down(s, off, 64);
        if ((threadIdx.x & 63) == 0) c2[i >> 6] = s;
    }
}

// kept for the fallback path
__global__ void __launch_bounds__(256)
cnorms_kernel(const float* __restrict__ vecs, float* __restrict__ c2) {
    int gwave = (blockIdx.x * 256 + threadIdx.x) >> 6;   // one wave per code row
    int lane  = threadIdx.x & 63;
    const float* src = vecs + (size_t)gwave * D_DIM;
    float4 v = ((const float4*)src)[lane];
    float s = v.x * v.x + v.y * v.y + v.z * v.z + v.w * v.w;
#pragma unroll
    for (int off = 32; off > 0; off >>= 1) s += __shfl_down(s, off, 64);
    if (lane == 0) c2[gwave] = s;
}

// ---------------- fast main kernel (all-register) ----------------

__global__ void __launch_bounds__(256, 2)
vq_main_fast(const _Float16* __restrict__ xh_g, const _Float16* __restrict__ xl_g,
             const _Float16* __restrict__ ch_g, const _Float16* __restrict__ cl_g,
             const float* __restrict__ c2, float* __restrict__ pd, int* __restrict__ pi) {
    __shared__ float rd[256];     // epilogue reduction only (2KB)
    __shared__ int   ri[256];

    const int t    = threadIdx.x;
    const int lane = t & 63;
    const int wv   = t >> 6;
    const int wy   = wv >> 1, wx = wv & 1;   // wave quadrant of 128x128
    const int fr   = lane & 15;              // row/col within 16x16 tile
    const int g    = lane >> 4;              // k-group 0..3

    const int split = blockIdx.x & (SPLITK - 1);
    const int pbase = (blockIdx.x >> 2) * TM;
    const int kbase = split * KCHUNK;

    // per-lane fragment base addresses. For MFMA f32_16x16x32_f16, lane
    // (fr,g) of A-frag i holds row (base + i*16 + fr), k-halves [g*8,g*8+8)
    // -> byte addr = row*512 + chunk*64 + g*16. Verified by r4-r11 (absmax 0).
    const char* xhp = (const char*)xh_g + (size_t)(pbase + wy * 64 + fr) * 512 + g * 16;
    const char* xlp = (const char*)xl_g + (size_t)(pbase + wy * 64 + fr) * 512 + g * 16;
    const char* chp = (const char*)ch_g + (size_t)(kbase + wx * 64 + fr) * 512 + g * 16;
    const char* clp = (const char*)cl_g + (size_t)(kbase + wx * 64 + fr) * 512 + g * 16;

    float best[16];
    int   bidx[16];
#pragma unroll
    for (int i = 0; i < 16; ++i) { best[i] = 3.4e38f; bidx[i] = 0; }

#pragma unroll 1
    for (int kt = 0; kt < NTILES; ++kt) {
        const size_t ktoff = (size_t)kt * (TN * 512);   // B tile stride (bytes)

        f32x4 acc[4][4];
#pragma unroll
        for (int i = 0; i < 4; ++i)
#pragma unroll
            for (int j = 0; j < 4; ++j) {
                f32x4 z = {0.f, 0.f, 0.f, 0.f};
                acc[i][j] = z;
            }

#pragma unroll 1
        for (int dkc = 0; dkc < 8; ++dkc) {             // BK=32-half chunks
            const int gofs = dkc * 64;                  // byte offset in row
            half8v a1[4], a3[4], b1[4], b2[4];
#pragma unroll
            for (int i = 0; i < 4; ++i) {
                a1[i] = *(const half8v*)(xhp + i * 8192 + gofs);   // xh
                a3[i] = *(const half8v*)(xlp + i * 8192 + gofs);   // xl*2^11
            }
#pragma unroll
            for (int j = 0; j < 4; ++j) {
                b1[j] = *(const half8v*)(chp + ktoff + j * 8192 + gofs);  // ch
                b2[j] = *(const half8v*)(clp + ktoff + j * 8192 + gofs);  // cl*2^11
            }
            half8v a2[4];
#pragma unroll
            for (int i = 0; i < 4; ++i)
                a2[i] = a1[i] * (_Float16)4.8828125e-4f;           // xh*2^-11
#pragma unroll
            for (int j = 0; j < 4; ++j) {
                half8v b3 = b1[j] * (_Float16)4.8828125e-4f;       // ch*2^-11
#pragma unroll
                for (int i = 0; i < 4; ++i) {
                    acc[i][j] = __builtin_amdgcn_mfma_f32_16x16x32_f16(a1[i], b1[j], acc[i][j], 0, 0, 0);
                    acc[i][j] = __builtin_amdgcn_mfma_f32_16x16x32_f16(a2[i], b2[j], acc[i][j], 0, 0, 0);
                    acc[i][j] = __builtin_amdgcn_mfma_f32_16x16x32_f16(a3[i], b3, acc[i][j], 0, 0, 0);
                }
            }
        }

        // merge tile into running argmin; ascending j + strict < == np first-min
        const int ktbase = kbase + kt * TN;
#pragma unroll
        for (int j = 0; j < 4; ++j) {
            const int cg = ktbase + wx * 64 + j * 16 + fr;
            const float c2v = c2[cg];
#pragma unroll
            for (int i = 0; i < 4; ++i)
#pragma unroll
                for (int r = 0; r < 4; ++r) {
                    const float v = fmaf(-2.0f, acc[i][j][r], c2v);
                    const int s = i * 4 + r;
                    if (v < best[s]) { best[s] = v; bidx[s] = cg; }
                }
        }
    }

    // reduce across the 16 lanes holding each point row, then the 2 wave-cols
    __syncthreads();
#pragma unroll
    for (int i = 0; i < 4; ++i)
#pragma unroll
        for (int r = 0; r < 4; ++r) {
            float bv = best[i * 4 + r];
            int   bi = bidx[i * 4 + r];
#pragma unroll
            for (int off = 1; off < 16; off <<= 1) {
                const float ov = __shfl_xor(bv, off, 64);
                const int   oi = __shfl_xor(bi, off, 64);
                if (ov < bv || (ov == bv && oi < bi)) { bv = ov; bi = oi; }
            }
            if (fr == 0) {
                const int rowl = wy * 64 + i * 16 + g * 4 + r;
                rd[rowl * 2 + wx] = bv;
                ri[rowl * 2 + wx] = bi;
            }
        }
    __syncthreads();
    if (t < TM) {
        float b0 = rd[t * 2];
        int   i0 = ri[t * 2];
        const float b1 = rd[t * 2 + 1];
        const int   i1 = ri[t * 2 + 1];
        if (b1 < b0 || (b1 == b0 && i1 < i0)) { b0 = b1; i0 = i1; }
        pd[split * N_PTS + pbase + t] = b0;
        pi[split * N_PTS + pbase + t] = i0;
    }
}

// ---------------- fallback (round-3, passing) ----------------

#define BK 32
#define LS (BK + 4)

__device__ inline half8v load8(const _Float16* p) {
    half4v a = *(const half4v*)p;
    half4v b = *(const half4v*)(p + 4);
    return __builtin_shufflevector(a, b, 0, 1, 2, 3, 4, 5, 6, 7);
}

struct Trip { _Float16 h, s2, l2; };

__device__ inline Trip cvt3(float v) {
    Trip t;
    _Float16 hh = (_Float16)v;
    float hf = (float)hh;
    t.h  = hh;
    t.s2 = (_Float16)(hf * 4.8828125e-4f);
    t.l2 = (_Float16)((v - hf) * 2048.0f);
    return t;
}

__global__ void __launch_bounds__(256, 2)
vq_main_v3(const float* __restrict__ x, const float* __restrict__ vecs,
           const float* __restrict__ c2, float* __restrict__ pd, int* __restrict__ pi) {
    __shared__ _Float16 lds[6 * TM * LS];
    _Float16* xh  = lds;
    _Float16* xs2 = lds + 1 * TM * LS;
    _Float16* xl2 = lds + 2 * TM * LS;
    _Float16* ch  = lds + 3 * TM * LS;
    _Float16* cl2 = lds + 4 * TM * LS;
    _Float16* cs2 = lds + 5 * TM * LS;

    const int t     = threadIdx.x;
    const int split = blockIdx.x & (SPLITK - 1);
    const int pbase = (blockIdx.x >> 2) * TM;
    const int kbase = split * KCHUNK;

    const int lane = t & 63;
    const int wv   = t >> 6;
    const int wy   = wv >> 1, wx = wv & 1;
    const int fr   = lane & 15;
    const int g    = lane >> 4;
    const int kb   = g * 8;

    const int srow = t >> 3;
    const int sc4  = (t & 7) * 4;

    float best[16];
    int   bidx[16];
#pragma unroll
    for (int i = 0; i < 16; ++i) { best[i] = 3.4e38f; bidx[i] = 0; }

    for (int kt = 0; kt < NTILES; ++kt) {
        const int ktbase = kbase + kt * TN;
        f32x4 acc[4][4];
#pragma unroll
        for (int i = 0; i < 4; ++i)
#pragma unroll
            for (int j = 0; j < 4; ++j) {
                f32x4 z = {0.f, 0.f, 0.f, 0.f};
                acc[i][j] = z;
            }
        for (int dk = 0; dk < D_DIM; dk += BK) {
            __syncthreads();
#pragma unroll
            for (int p = 0; p < 4; ++p) {
                const int row = srow + p * 32;
                const float4 v = *(const float4*)&x[(size_t)(pbase + row) * D_DIM + dk + sc4];
                const Trip t0 = cvt3(v.x), t1 = cvt3(v.y), t2 = cvt3(v.z), t3 = cvt3(v.w);
                half4v h  = {t0.h,  t1.h,  t2.h,  t3.h};
                half4v s2 = {t0.s2, t1.s2, t2.s2, t3.s2};
                half4v l2 = {t0.l2, t1.l2, t2.l2, t3.l2};
                *(half4v*)&xh [row * LS + sc4] = h;
                *(half4v*)&xs2[row * LS + sc4] = s2;
                *(half4v*)&xl2[row * LS + sc4] = l2;
                const float4 w = *(const float4*)&vecs[(size_t)(ktbase + row) * D_DIM + dk + sc4];
                const Trip u0 = cvt3(w.x), u1 = cvt3(w.y), u2 = cvt3(w.z), u3 = cvt3(w.w);
                half4v hc = {u0.h,  u1.h,  u2.h,  u3.h};
                half4v sc = {u0.s2, u1.s2, u2.s2, u3.s2};
                half4v lc = {u0.l2, u1.l2, u2.l2, u3.l2};
                *(half4v*)&ch [row * LS + sc4] = hc;
                *(half4v*)&cs2[row * LS + sc4] = sc;
                *(half4v*)&cl2[row * LS + sc4] = lc;
            }
            __syncthreads();
            half8v a1[4], a2[4], a3[4], b1[4], b2[4], b3[4];
#pragma unroll
            for (int i = 0; i < 4; ++i) {
                const int aoff = (wy * 64 + i * 16 + fr) * LS + kb;
                a1[i] = load8(&xh [aoff]);
                a2[i] = load8(&xs2[aoff]);
                a3[i] = load8(&xl2[aoff]);
                const int boff2 = (wx * 64 + i * 16 + fr) * LS + kb;
                b1[i] = load8(&ch [boff2]);
                b2[i] = load8(&cl2[boff2]);
                b3[i] = load8(&cs2[boff2]);
            }
#pragma unroll
            for (int i = 0; i < 4; ++i)
#pragma unroll
                for (int j = 0; j < 4; ++j) {
                    acc[i][j] = __builtin_amdgcn_mfma_f32_16x16x32_f16(a1[i], b1[j], acc[i][j], 0, 0, 0);
                    acc[i][j] = __builtin_amdgcn_mfma_f32_16x16x32_f16(a2[i], b2[j], acc[i][j], 0, 0, 0);
                    acc[i][j] = __builtin_amdgcn_mfma_f32_16x16x32_f16(a3[i], b3[j], acc[i][j], 0, 0, 0);
                }
        }
#pragma unroll
        for (int j = 0; j < 4; ++j) {
            const int cg = ktbase + wx * 64 + j * 16 + fr;
            const float c2v = c2[cg];
#pragma unroll
            for (int i = 0; i < 4; ++i)
#pragma unroll
                for (int r = 0; r < 4; ++r) {
                    const float v = fmaf(-2.0f, acc[i][j][r], c2v);
                    const int s = i * 4 + r;
                    if (v < best[s]) { best[s] = v; bidx[s] = cg; }
                }
        }
    }
    __syncthreads();
    float* rd = (float*)lds;
    int*   ri = (int*)lds + 256;
#pragma unroll
    for (int i = 0; i < 4; ++i)
#pragma unroll
        for (int r = 0; r < 4; ++r) {
            float bv = best[i * 4 + r];
            int   bi = bidx[i * 4 + r];
#pragma unroll
            for (int off = 1; off < 16; off <<= 1) {
                const float ov = __shfl_xor(bv, off, 64);
                const int   oi = __shfl_xor(bi, off, 64);
                if (ov < bv || (ov == bv && oi < bi)) { bv = ov; bi = oi; }
            }
            if (fr == 0) {
                const int rowl = wy * 64 + i * 16 + g * 4 + r;
                rd[rowl * 2 + wx] = bv;
                ri[rowl * 2 + wx] = bi;
            }
        }
    __syncthreads();
    if (t < TM) {
        float b0 = rd[t * 2];
        int   i0 = ri[t * 2];
        const float b1 = rd[t * 2 + 1];
        const int   i1 = ri[t * 2 + 1];
        if (b1 < b0 || (b1 == b0 && i1 < i0)) { b0 = b1; i0 = i1; }
        pd[split * N_PTS + pbase + t] = b0;
        pi[split * N_PTS + pbase + t] = i0;
    }
}

// ---------------- combine ----------------

__global__ void __launch_bounds__(256)
vq_combine(const float* __restrict__ pd, const int* __restrict__ pi,
           int* __restrict__ out) {
    const int p = blockIdx.x * 256 + threadIdx.x;
    float bb = pd[p];
    int   bi = pi[p];
#pragma unroll
    for (int s = 1; s < SPLITK; ++s) {
        const float v  = pd[s * N_PTS + p];
        const int   vi = pi[s * N_PTS + p];
        if (v < bb || (v == bb && vi < bi)) { bb = v; bi = vi; }
    }
    out[p] = bi;
}

extern "C" void kernel_launch(void* const* d_in, const int* in_sizes, int n_in,
                              void* d_out, int out_size, void* d_ws, size_t ws_size,
                              hipStream_t stream) {
    const float* x    = (const float*)d_in[0];
    const float* vecs = (const float*)d_in[1];
    int* out = (int*)d_out;
    char* ws = (char*)d_ws;

    if (ws_size >= (size_t)WS_END) {
        _Float16* xh = (_Float16*)(ws + WS_XH);
        _Float16* xl = (_Float16*)(ws + WS_XL);
        _Float16* ch = (_Float16*)(ws + WS_CH);
        _Float16* cl = (_Float16*)(ws + WS_CL);
        float* c2 = (float*)(ws + WS_C2);
        float* pd = (float*)(ws + WS_PD);
        int*   pi = (int*)(ws + WS_PI);

        hipLaunchKernelGGL(prep_kernel, dim3(XBLOCKS + CBLOCKS), dim3(256), 0, stream,
                           x, vecs, xh, xl, ch, cl, c2);
        hipLaunchKernelGGL(vq_main_fast, dim3((N_PTS / TM) * SPLITK), dim3(256), 0, stream,
                           xh, xl, ch, cl, c2, pd, pi);
        hipLaunchKernelGGL(vq_combine, dim3(N_PTS / 256), dim3(256), 0, stream,
                           pd, pi, out);
    } else {
        float* c2 = (float*)ws;
        float* pd = (float*)ws + K_CB;
        int*   pi = (int*)((float*)ws + K_CB + SPLITK * N_PTS);
        hipLaunchKernelGGL(cnorms_kernel, dim3(K_CB / 4), dim3(256), 0, stream,
                           vecs, c2);
        hipLaunchKernelGGL(vq_main_v3, dim3((N_PTS / TM) * SPLITK), dim3(256), 0, stream,
                           x, vecs, c2, pd, pi);
        hipLaunchKernelGGL(vq_combine, dim3(N_PTS / 256), dim3(256), 0, stream,
                           pd, pi, out);
    }
}

// Round 9
// 505.751 us; speedup vs baseline: 1.9635x; 1.9635x over previous
//
#include <hip/hip_runtime.h>
#include <stdint.h>
#include <stddef.h>

// VectorQuantization — N=32768, K=8192, D=256 fp32 -> int32 argmin.
// Round 13: hybrid operand path. Established: wall = MFMA(199µs) + LDS
// port(219µs) SERIALIZED (r4-r11); all-global is latency-bound (r12, 17%
// MfmaUtil). Fix the traffic, not the schedule: codes (shared by 4 waves)
// stay LDS-staged (gld16 + r8's proven conflict-free swizzle); x fragments
// (wave-private) come from a PACKED global layout straight into registers —
// prep writes xh/xl in per-lane fragment order so each wave chunk is one
// contiguous coalesced 1KB segment, L1/L2-resident (x repeats every kt).
// LDS reads halve (164->82µs), DMA writes halve (55->27) -> LDS port 110µs
// << MFMA 199µs: serialized floor ~230µs. Pipeline: 3x16KB code buffers,
// ONE barrier/chunk (stage target disjoint from cur and prev-read buffers),
// counted vmcnt(12) (4 gld16 + 8 xloads/iter), sched_barrier fences,
// setprio(1) around the MFMA cluster (T5). Chunk order, j-outer/i-inner,
// 3-term accumulation identical to r4/r8/r11 -> bit-identical results.
// Fallback to the (passing) round-3 kernel if ws_size < 43MB.

#define N_PTS 32768
#define K_CB  8192
#define D_DIM 256
#define TM 128
#define TN 128
#define SPLITK 4
#define KCHUNK (K_CB / SPLITK)   // 2048
#define NTILES (KCHUNK / TN)     // 16
#define NCHUNKS (NTILES * 8)     // 128 BK=32 chunks per block

// fast-path ws layout (byte offsets; all 16B-aligned). xh/xl are PACKED:
// [row/64][kchunk 0..7][row%64][slot 0..3 (16B)] — same total bytes.
#define WS_XH   0
#define WS_XL   (WS_XH + N_PTS * D_DIM * 2)
#define WS_CH   (WS_XL + N_PTS * D_DIM * 2)
#define WS_CL   (WS_CH + K_CB * D_DIM * 2)
#define WS_C2   (WS_CL + K_CB * D_DIM * 2)
#define WS_PD   (WS_C2 + K_CB * 4)
#define WS_PI   (WS_PD + SPLITK * N_PTS * 4)
#define WS_END  (WS_PI + SPLITK * N_PTS * 4)   // 43,024,384 B

typedef _Float16 half4v __attribute__((ext_vector_type(4)));
typedef _Float16 half8v __attribute__((ext_vector_type(8)));
typedef float    f32x4  __attribute__((ext_vector_type(4)));

__device__ __forceinline__ void gld16(const void* g, void* l) {
    __builtin_amdgcn_global_load_lds(
        (const __attribute__((address_space(1))) void*)g,
        (__attribute__((address_space(3))) void*)l, 16, 0, 0);
}

// ---------------- preprocessing (fused: split x (packed), codes + norms) ---

#define XBLOCKS (N_PTS * D_DIM / 4 / 256)   // 8192
#define CBLOCKS (K_CB * D_DIM / 4 / 256)    // 2048

__global__ void __launch_bounds__(256)
prep_kernel(const float* __restrict__ x, const float* __restrict__ vecs,
            _Float16* __restrict__ xh, _Float16* __restrict__ xl,
            _Float16* __restrict__ ch, _Float16* __restrict__ cl,
            float* __restrict__ c2) {
    const int b = blockIdx.x;
    if (b < XBLOCKS) {
        const int i = b * 256 + threadIdx.x;           // one float4 per thread
        const float4 v = ((const float4*)x)[i];
        half4v h = {(_Float16)v.x, (_Float16)v.y, (_Float16)v.z, (_Float16)v.w};
        half4v l = {(_Float16)((v.x - (float)h[0]) * 2048.0f),
                    (_Float16)((v.y - (float)h[1]) * 2048.0f),
                    (_Float16)((v.z - (float)h[2]) * 2048.0f),
                    (_Float16)((v.w - (float)h[3]) * 2048.0f)};
        // packed fragment layout: row r, k k0 ->
        // ((r>>6)*8 + (k0>>5))*4096 + (r&63)*64 + ((k0>>3)&3)*16 + (k0&7)*2
        const int f   = i * 4;
        const int row = f >> 8, k0 = f & 255;
        const size_t pa = ((size_t)(row >> 6) * 8 + (k0 >> 5)) * 4096
                        + (row & 63) * 64 + ((k0 >> 3) & 3) * 16 + (k0 & 7) * 2;
        *(half4v*)((char*)xh + pa) = h;
        *(half4v*)((char*)xl + pa) = l;
    } else {
        const int i = (b - XBLOCKS) * 256 + threadIdx.x;
        const float4 v = ((const float4*)vecs)[i];
        half4v h = {(_Float16)v.x, (_Float16)v.y, (_Float16)v.z, (_Float16)v.w};
        half4v l = {(_Float16)((v.x - (float)h[0]) * 2048.0f),
                    (_Float16)((v.y - (float)h[1]) * 2048.0f),
                    (_Float16)((v.z - (float)h[2]) * 2048.0f),
                    (_Float16)((v.w - (float)h[3]) * 2048.0f)};
        *(half4v*)(ch + (size_t)i * 4) = h;
        *(half4v*)(cl + (size_t)i * 4) = l;
        // one wave == one code row -> norm (identical tree -> bit-identical c2)
        float s = v.x * v.x + v.y * v.y + v.z * v.z + v.w * v.w;
#pragma unroll
        for (int off = 32; off > 0; off >>= 1) s += __shfl_down(s, off, 64);
        if ((threadIdx.x & 63) == 0) c2[i >> 6] = s;
    }
}

// kept for the fallback path
__global__ void __launch_bounds__(256)
cnorms_kernel(const float* __restrict__ vecs, float* __restrict__ c2) {
    int gwave = (blockIdx.x * 256 + threadIdx.x) >> 6;   // one wave per code row
    int lane  = threadIdx.x & 63;
    const float* src = vecs + (size_t)gwave * D_DIM;
    float4 v = ((const float4*)src)[lane];
    float s = v.x * v.x + v.y * v.y + v.z * v.z + v.w * v.w;
#pragma unroll
    for (int off = 32; off > 0; off >>= 1) s += __shfl_down(s, off, 64);
    if (lane == 0) c2[gwave] = s;
}

// ---------------- fast main kernel (codes in LDS, x in registers) ---------

__global__ void __launch_bounds__(256, 2)
vq_main_fast(const _Float16* __restrict__ xh_p, const _Float16* __restrict__ xl_p,
             const _Float16* __restrict__ ch_g, const _Float16* __restrict__ cl_g,
             const float* __restrict__ c2, float* __restrict__ pd, int* __restrict__ pi) {
    // three 16KB code buffers; per buffer: ch [0,8K) cl [8K,16K).
    // 64B rows; k-slot s of row r holds k-group s ^ ((r>>1)&3) (r8 swizzle,
    // measured conflict-free: SQ_LDS_BANK_CONFLICT 8129).
    __shared__ __align__(16) char lds[49152];

    const int t    = threadIdx.x;
    const int lane = t & 63;
    const int wv   = t >> 6;
    const int wy   = wv >> 1, wx = wv & 1;   // wave quadrant of 128x128
    const int fr   = lane & 15;              // row/col within 16x16 tile
    const int g    = lane >> 4;              // k-group 0..3

    const int split = blockIdx.x & (SPLITK - 1);
    const int pbase = (blockIdx.x >> 2) * TM;
    const int kbase = split * KCHUNK;

    // codes staging: per-lane pre-swizzled GLOBAL source (DMA dest linear):
    // lane i fetches k-slot (i&3)^((i>>3)&3) of row i>>2.
    const int srowoff = (lane >> 2) * 512
                      + ((((lane & 3) ^ ((lane >> 3) & 3))) << 4);
    const char* ch_s = (const char*)ch_g + (size_t)(kbase + wv * 32) * 512 + srowoff;
    const char* cl_s = (const char*)cl_g + (size_t)(kbase + wv * 32) * 512 + srowoff;
    const int stW = wv * 2048;               // wave staging base within region

    // x packed fragment base: grp = row/64 for this wave's 64-row strip
    const int grp = (blockIdx.x >> 2) * 2 + wy;
    const char* xhp = (const char*)xh_p + (size_t)grp * 32768 + fr * 64 + g * 16;
    const char* xlp = (const char*)xl_p + (size_t)grp * 32768 + fr * 64 + g * 16;

    // B fragment LDS byte offsets: row*64 + swizzled slot
    const int skey = (fr >> 1) & 3;
    int boff[4];
#pragma unroll
    for (int j = 0; j < 4; ++j)
        boff[j] = (wx * 64 + j * 16 + fr) * 64 + ((g ^ skey) << 4);

    f32x4 acc[4][4];
    half8v a1A[4], a3A[4], a1B[4], a3B[4];

    auto STAGE = [&](int bw, int c) {        // 4 gld16 per wave
        const size_t kofs = (size_t)(c >> 3) * (TN * 512);
        const int gofs = (c & 7) * 64;
        char* B = lds + bw * 16384;
        gld16(ch_s + kofs + gofs,        B +        stW);
        gld16(ch_s + kofs + gofs + 8192, B +        stW + 1024);
        gld16(cl_s + kofs + gofs,        B + 8192 + stW);
        gld16(cl_s + kofs + gofs + 8192, B + 8192 + stW + 1024);
    };

    auto XLOAD = [&](half8v* a1, half8v* a3, int c) {   // 8 coalesced 16B loads
        const int xofs = (c & 7) * 4096;
#pragma unroll
        for (int i = 0; i < 4; ++i) {
            a1[i] = *(const half8v*)(xhp + xofs + i * 1024);
            a3[i] = *(const half8v*)(xlp + xofs + i * 1024);
        }
    };

    auto COMPUTE = [&](int br, const half8v* a1, const half8v* a3) {
        const char* B = lds + br * 16384;
        half8v a2[4];
#pragma unroll
        for (int i = 0; i < 4; ++i)
            a2[i] = a1[i] * (_Float16)4.8828125e-4f;    // xh*2^-11
#pragma unroll
        for (int j = 0; j < 4; ++j) {
            const char* p = B + boff[j];
            half8v b1 = *(const half8v*)p;              // ch
            half8v b2 = *(const half8v*)(p + 8192);     // cl*2^11
            half8v b3 = b1 * (_Float16)4.8828125e-4f;   // ch*2^-11
#pragma unroll
            for (int i = 0; i < 4; ++i) {
                acc[i][j] = __builtin_amdgcn_mfma_f32_16x16x32_f16(a1[i], b1, acc[i][j], 0, 0, 0);
                acc[i][j] = __builtin_amdgcn_mfma_f32_16x16x32_f16(a2[i], b2, acc[i][j], 0, 0, 0);
                acc[i][j] = __builtin_amdgcn_mfma_f32_16x16x32_f16(a3[i], b3, acc[i][j], 0, 0, 0);
            }
        }
    };

    float best[16];
    int   bidx[16];
#pragma unroll
    for (int i = 0; i < 16; ++i) { best[i] = 3.4e38f; bidx[i] = 0; }

    STAGE(0, 0);                   // prologue: chunk 0 codes + x in flight
    XLOAD(a1A, a3A, 0);
    int br = 0;                    // read-buffer index (rotates mod 3)

#pragma unroll 1
    for (int kt = 0; kt < NTILES; ++kt) {
#pragma unroll
        for (int i = 0; i < 4; ++i)
#pragma unroll
            for (int j = 0; j < 4; ++j) {
                f32x4 z = {0.f, 0.f, 0.f, 0.f};
                acc[i][j] = z;
            }

#pragma unroll 1
        for (int du = 0; du < 4; ++du) {
            int c = kt * 8 + du * 2;
            // ---- even chunk: compute A-set, prefetch into B-set ----
            int bw = (br == 2) ? 0 : br + 1;
            if (c + 1 < NCHUNKS) {
                STAGE(bw, c + 1);
                XLOAD(a1B, a3B, c + 1);
                __builtin_amdgcn_sched_barrier(0);
                asm volatile("s_waitcnt vmcnt(12)" ::: "memory");
            } else {
                __builtin_amdgcn_sched_barrier(0);
                asm volatile("s_waitcnt vmcnt(0)" ::: "memory");
            }
            __builtin_amdgcn_sched_barrier(0);
            __builtin_amdgcn_s_barrier();     // all waves' chunk-c DMA landed
            __builtin_amdgcn_sched_barrier(0);
            __builtin_amdgcn_s_setprio(1);
            COMPUTE(br, a1A, a3A);
            __builtin_amdgcn_s_setprio(0);
            br = bw;
            // ---- odd chunk: compute B-set, prefetch into A-set ----
            c = c + 1;
            bw = (br == 2) ? 0 : br + 1;
            if (c + 1 < NCHUNKS) {
                STAGE(bw, c + 1);
                XLOAD(a1A, a3A, c + 1);
                __builtin_amdgcn_sched_barrier(0);
                asm volatile("s_waitcnt vmcnt(12)" ::: "memory");
            } else {
                __builtin_amdgcn_sched_barrier(0);
                asm volatile("s_waitcnt vmcnt(0)" ::: "memory");
            }
            __builtin_amdgcn_sched_barrier(0);
            __builtin_amdgcn_s_barrier();
            __builtin_amdgcn_sched_barrier(0);
            __builtin_amdgcn_s_setprio(1);
            COMPUTE(br, a1B, a3B);
            __builtin_amdgcn_s_setprio(0);
            br = bw;
        }

        // merge tile into running argmin; ascending j + strict < == np first-min
        const int ktbase = kbase + kt * TN;
#pragma unroll
        for (int j = 0; j < 4; ++j) {
            const int cg = ktbase + wx * 64 + j * 16 + fr;
            const float c2v = c2[cg];
#pragma unroll
            for (int i = 0; i < 4; ++i)
#pragma unroll
                for (int r = 0; r < 4; ++r) {
                    const float v = fmaf(-2.0f, acc[i][j][r], c2v);
                    const int s = i * 4 + r;
                    if (v < best[s]) { best[s] = v; bidx[s] = cg; }
                }
        }
    }

    // reduce across the 16 lanes holding each point row, then the 2 wave-cols
    __syncthreads();
    float* rd = (float*)lds;          // 128 x 2 floats
    int*   ri = (int*)lds + 256;      // 128 x 2 ints
#pragma unroll
    for (int i = 0; i < 4; ++i)
#pragma unroll
        for (int r = 0; r < 4; ++r) {
            float bv = best[i * 4 + r];
            int   bi = bidx[i * 4 + r];
#pragma unroll
            for (int off = 1; off < 16; off <<= 1) {
                const float ov = __shfl_xor(bv, off, 64);
                const int   oi = __shfl_xor(bi, off, 64);
                if (ov < bv || (ov == bv && oi < bi)) { bv = ov; bi = oi; }
            }
            if (fr == 0) {
                const int rowl = wy * 64 + i * 16 + g * 4 + r;
                rd[rowl * 2 + wx] = bv;
                ri[rowl * 2 + wx] = bi;
            }
        }
    __syncthreads();
    if (t < TM) {
        float b0 = rd[t * 2];
        int   i0 = ri[t * 2];
        const float b1 = rd[t * 2 + 1];
        const int   i1 = ri[t * 2 + 1];
        if (b1 < b0 || (b1 == b0 && i1 < i0)) { b0 = b1; i0 = i1; }
        pd[split * N_PTS + pbase + t] = b0;
        pi[split * N_PTS + pbase + t] = i0;
    }
}

// ---------------- fallback (round-3, passing) ----------------

#define BK 32
#define LS (BK + 4)

__device__ inline half8v load8(const _Float16* p) {
    half4v a = *(const half4v*)p;
    half4v b = *(const half4v*)(p + 4);
    return __builtin_shufflevector(a, b, 0, 1, 2, 3, 4, 5, 6, 7);
}

struct Trip { _Float16 h, s2, l2; };

__device__ inline Trip cvt3(float v) {
    Trip t;
    _Float16 hh = (_Float16)v;
    float hf = (float)hh;
    t.h  = hh;
    t.s2 = (_Float16)(hf * 4.8828125e-4f);
    t.l2 = (_Float16)((v - hf) * 2048.0f);
    return t;
}

__global__ void __launch_bounds__(256, 2)
vq_main_v3(const float* __restrict__ x, const float* __restrict__ vecs,
           const float* __restrict__ c2, float* __restrict__ pd, int* __restrict__ pi) {
    __shared__ _Float16 lds[6 * TM * LS];
    _Float16* xh  = lds;
    _Float16* xs2 = lds + 1 * TM * LS;
    _Float16* xl2 = lds + 2 * TM * LS;
    _Float16* ch  = lds + 3 * TM * LS;
    _Float16* cl2 = lds + 4 * TM * LS;
    _Float16* cs2 = lds + 5 * TM * LS;

    const int t     = threadIdx.x;
    const int split = blockIdx.x & (SPLITK - 1);
    const int pbase = (blockIdx.x >> 2) * TM;
    const int kbase = split * KCHUNK;

    const int lane = t & 63;
    const int wv   = t >> 6;
    const int wy   = wv >> 1, wx = wv & 1;
    const int fr   = lane & 15;
    const int g    = lane >> 4;
    const int kb   = g * 8;

    const int srow = t >> 3;
    const int sc4  = (t & 7) * 4;

    float best[16];
    int   bidx[16];
#pragma unroll
    for (int i = 0; i < 16; ++i) { best[i] = 3.4e38f; bidx[i] = 0; }

    for (int kt = 0; kt < NTILES; ++kt) {
        const int ktbase = kbase + kt * TN;
        f32x4 acc[4][4];
#pragma unroll
        for (int i = 0; i < 4; ++i)
#pragma unroll
            for (int j = 0; j < 4; ++j) {
                f32x4 z = {0.f, 0.f, 0.f, 0.f};
                acc[i][j] = z;
            }
        for (int dk = 0; dk < D_DIM; dk += BK) {
            __syncthreads();
#pragma unroll
            for (int p = 0; p < 4; ++p) {
                const int row = srow + p * 32;
                const float4 v = *(const float4*)&x[(size_t)(pbase + row) * D_DIM + dk + sc4];
                const Trip t0 = cvt3(v.x), t1 = cvt3(v.y), t2 = cvt3(v.z), t3 = cvt3(v.w);
                half4v h  = {t0.h,  t1.h,  t2.h,  t3.h};
                half4v s2 = {t0.s2, t1.s2, t2.s2, t3.s2};
                half4v l2 = {t0.l2, t1.l2, t2.l2, t3.l2};
                *(half4v*)&xh [row * LS + sc4] = h;
                *(half4v*)&xs2[row * LS + sc4] = s2;
                *(half4v*)&xl2[row * LS + sc4] = l2;
                const float4 w = *(const float4*)&vecs[(size_t)(ktbase + row) * D_DIM + dk + sc4];
                const Trip u0 = cvt3(w.x), u1 = cvt3(w.y), u2 = cvt3(w.z), u3 = cvt3(w.w);
                half4v hc = {u0.h,  u1.h,  u2.h,  u3.h};
                half4v sc = {u0.s2, u1.s2, u2.s2, u3.s2};
                half4v lc = {u0.l2, u1.l2, u2.l2, u3.l2};
                *(half4v*)&ch [row * LS + sc4] = hc;
                *(half4v*)&cs2[row * LS + sc4] = sc;
                *(half4v*)&cl2[row * LS + sc4] = lc;
            }
            __syncthreads();
            half8v a1[4], a2[4], a3[4], b1[4], b2[4], b3[4];
#pragma unroll
            for (int i = 0; i < 4; ++i) {
                const int aoff = (wy * 64 + i * 16 + fr) * LS + kb;
                a1[i] = load8(&xh [aoff]);
                a2[i] = load8(&xs2[aoff]);
                a3[i] = load8(&xl2[aoff]);
                const int boff2 = (wx * 64 + i * 16 + fr) * LS + kb;
                b1[i] = load8(&ch [boff2]);
                b2[i] = load8(&cl2[boff2]);
                b3[i] = load8(&cs2[boff2]);
            }
#pragma unroll
            for (int i = 0; i < 4; ++i)
#pragma unroll
                for (int j = 0; j < 4; ++j) {
                    acc[i][j] = __builtin_amdgcn_mfma_f32_16x16x32_f16(a1[i], b1[j], acc[i][j], 0, 0, 0);
                    acc[i][j] = __builtin_amdgcn_mfma_f32_16x16x32_f16(a2[i], b2[j], acc[i][j], 0, 0, 0);
                    acc[i][j] = __builtin_amdgcn_mfma_f32_16x16x32_f16(a3[i], b3[j], acc[i][j], 0, 0, 0);
                }
        }
#pragma unroll
        for (int j = 0; j < 4; ++j) {
            const int cg = ktbase + wx * 64 + j * 16 + fr;
            const float c2v = c2[cg];
#pragma unroll
            for (int i = 0; i < 4; ++i)
#pragma unroll
                for (int r = 0; r < 4; ++r) {
                    const float v = fmaf(-2.0f, acc[i][j][r], c2v);
                    const int s = i * 4 + r;
                    if (v < best[s]) { best[s] = v; bidx[s] = cg; }
                }
        }
    }
    __syncthreads();
    float* rd = (float*)lds;
    int*   ri = (int*)lds + 256;
#pragma unroll
    for (int i = 0; i < 4; ++i)
#pragma unroll
        for (int r = 0; r < 4; ++r) {
            float bv = best[i * 4 + r];
            int   bi = bidx[i * 4 + r];
#pragma unroll
            for (int off = 1; off < 16; off <<= 1) {
                const float ov = __shfl_xor(bv, off, 64);
                const int   oi = __shfl_xor(bi, off, 64);
                if (ov < bv || (ov == bv && oi < bi)) { bv = ov; bi = oi; }
            }
            if (fr == 0) {
                const int rowl = wy * 64 + i * 16 + g * 4 + r;
                rd[rowl * 2 + wx] = bv;
                ri[rowl * 2 + wx] = bi;
            }
        }
    __syncthreads();
    if (t < TM) {
        float b0 = rd[t * 2];
        int   i0 = ri[t * 2];
        const float b1 = rd[t * 2 + 1];
        const int   i1 = ri[t * 2 + 1];
        if (b1 < b0 || (b1 == b0 && i1 < i0)) { b0 = b1; i0 = i1; }
        pd[split * N_PTS + pbase + t] = b0;
        pi[split * N_PTS + pbase + t] = i0;
    }
}

// ---------------- combine ----------------

__global__ void __launch_bounds__(256)
vq_combine(const float* __restrict__ pd, const int* __restrict__ pi,
           int* __restrict__ out) {
    const int p = blockIdx.x * 256 + threadIdx.x;
    float bb = pd[p];
    int   bi = pi[p];
#pragma unroll
    for (int s = 1; s < SPLITK; ++s) {
        const float v  = pd[s * N_PTS + p];
        const int   vi = pi[s * N_PTS + p];
        if (v < bb || (v == bb && vi < bi)) { bb = v; bi = vi; }
    }
    out[p] = bi;
}

extern "C" void kernel_launch(void* const* d_in, const int* in_sizes, int n_in,
                              void* d_out, int out_size, void* d_ws, size_t ws_size,
                              hipStream_t stream) {
    const float* x    = (const float*)d_in[0];
    const float* vecs = (const float*)d_in[1];
    int* out = (int*)d_out;
    char* ws = (char*)d_ws;

    if (ws_size >= (size_t)WS_END) {
        _Float16* xh = (_Float16*)(ws + WS_XH);
        _Float16* xl = (_Float16*)(ws + WS_XL);
        _Float16* ch = (_Float16*)(ws + WS_CH);
        _Float16* cl = (_Float16*)(ws + WS_CL);
        float* c2 = (float*)(ws + WS_C2);
        float* pd = (float*)(ws + WS_PD);
        int*   pi = (int*)(ws + WS_PI);

        hipLaunchKernelGGL(prep_kernel, dim3(XBLOCKS + CBLOCKS), dim3(256), 0, stream,
                           x, vecs, xh, xl, ch, cl, c2);
        hipLaunchKernelGGL(vq_main_fast, dim3((N_PTS / TM) * SPLITK), dim3(256), 0, stream,
                           xh, xl, ch, cl, c2, pd, pi);
        hipLaunchKernelGGL(vq_combine, dim3(N_PTS / 256), dim3(256), 0, stream,
                           pd, pi, out);
    } else {
        float* c2 = (float*)ws;
        float* pd = (float*)ws + K_CB;
        int*   pi = (int*)((float*)ws + K_CB + SPLITK * N_PTS);
        hipLaunchKernelGGL(cnorms_kernel, dim3(K_CB / 4), dim3(256), 0, stream,
                           vecs, c2);
        hipLaunchKernelGGL(vq_main_v3, dim3((N_PTS / TM) * SPLITK), dim3(256), 0, stream,
                           x, vecs, c2, pd, pi);
        hipLaunchKernelGGL(vq_combine, dim3(N_PTS / 256), dim3(256), 0, stream,
                           pd, pi, out);
    }
}